// Round 4
// baseline (66.007 us; speedup 1.0000x reference)
//
#include <hip/hip_runtime.h>
#include <hip/hip_bf16.h>

// Problem constants
#define PP     4096      // P assets
#define BB     2         // batch
#define DD     128       // model dim
#define NH     4         // heads
#define HDIM   32        // head dim
#define MROWS  8192      // B*P
#define MAXN   24        // max neighbors kept (true max is 17)
#define RPB    16        // attn rows per block

typedef __attribute__((ext_vector_type(8))) short short8;   // 8 bf16 = 4 VGPR
typedef __attribute__((ext_vector_type(4))) float floatx4;  // MFMA acc

__device__ __forceinline__ unsigned short f2bf(float f) {
  __hip_bfloat16 h = __float2bfloat16(f);
  return *reinterpret_cast<unsigned short*>(&h);
}

// ---------------------------------------------------------------------------
// Mask dtype detection (0 = u8/bool, 1 = int32, 2 = float32) — see round 1.
__device__ __forceinline__ int detect_mode(const unsigned char* mask) {
  bool u8ok = true, f32ok = true;
#pragma unroll
  for (int p = 1; p <= 3; ++p) {
    size_t f = (size_t)p * PP + p;
    u8ok = u8ok && (mask[f] == 1);
    unsigned int dw = reinterpret_cast<const unsigned int*>(mask)[f];
    f32ok = f32ok && (dw == 0x3f800000u);
  }
  return u8ok ? 0 : (f32ok ? 2 : 1);
}

// ---------------------------------------------------------------------------
// Kernel 1: compact one mask row per block (64 threads = 1 wave).
// Blocks 0..255 additionally convert the 4 weight matrices to bf16 (1 float4
// per thread).
__global__ void compact_kernel(const void* __restrict__ mask,
                               const float4* __restrict__ Wq,
                               const float4* __restrict__ Wk,
                               const float4* __restrict__ Wv,
                               const float4* __restrict__ Wo,
                               int* __restrict__ nbr_idx,
                               int* __restrict__ nbr_cnt,
                               unsigned short* __restrict__ Wb) {
  int p = blockIdx.x;
  int lane = threadIdx.x;  // 0..63

  if (p < 256) {  // weight conversion: 16384 float4 units total
    int u = p * 64 + lane;
    int m = u >> 12, off = u & 4095;
    const float4* Ws = m == 0 ? Wq : (m == 1 ? Wk : (m == 2 ? Wv : Wo));
    float4 v = Ws[off];
    ushort4 o;
    o.x = f2bf(v.x); o.y = f2bf(v.y); o.z = f2bf(v.z); o.w = f2bf(v.w);
    *reinterpret_cast<ushort4*>(Wb + (size_t)m * DD * DD + (size_t)off * 4) = o;
  }

  int md = detect_mode((const unsigned char*)mask);
  unsigned long long bits = 0ULL;  // bit i => column lane*64+i is a neighbor

  if (md == 0) {
    const uint4* base =
        reinterpret_cast<const uint4*>((const unsigned char*)mask + (size_t)p * PP) +
        lane * 4;
#pragma unroll
    for (int c = 0; c < 4; ++c) {
      uint4 v = base[c];
      unsigned int w4[4] = {v.x, v.y, v.z, v.w};
#pragma unroll
      for (int wi = 0; wi < 4; ++wi) {
        unsigned int w = w4[wi];
        unsigned int nz = ((((w & 0x7F7F7F7Fu) + 0x7F7F7F7Fu) | w) & 0x80808080u);
        unsigned int x = (nz >> 7) & 0x01010101u;
        unsigned int b4 = (x | (x >> 7) | (x >> 14) | (x >> 21)) & 0xFu;
        bits |= (unsigned long long)b4 << (c * 16 + wi * 4);
      }
    }
  } else if (md == 1) {
    const uint4* base =
        reinterpret_cast<const uint4*>((const int*)mask + (size_t)p * PP) + lane * 16;
#pragma unroll
    for (int c = 0; c < 16; ++c) {
      uint4 v = base[c];
      unsigned long long b = (v.x ? 1u : 0u) | (v.y ? 2u : 0u) |
                             (v.z ? 4u : 0u) | (v.w ? 8u : 0u);
      bits |= b << (c * 4);
    }
  } else {
    const float4* base =
        reinterpret_cast<const float4*>((const float*)mask + (size_t)p * PP) + lane * 16;
#pragma unroll
    for (int c = 0; c < 16; ++c) {
      float4 v = base[c];
      unsigned long long b = (v.x != 0.f ? 1u : 0u) | (v.y != 0.f ? 2u : 0u) |
                             (v.z != 0.f ? 4u : 0u) | (v.w != 0.f ? 8u : 0u);
      bits |= b << (c * 4);
    }
  }

  int cnt = __popcll(bits);
  int pre = cnt;
#pragma unroll
  for (int d = 1; d < 64; d <<= 1) {
    int t = __shfl_up(pre, d);
    if (lane >= d) pre += t;
  }
  int base_pos = pre - cnt;  // exclusive prefix
  unsigned long long m = bits;
  while (m) {
    int b = __ffsll((long long)m) - 1;
    m &= m - 1;
    if (base_pos < MAXN) nbr_idx[p * MAXN + base_pos] = lane * 64 + b;
    ++base_pos;
  }
  int total = __shfl(pre, 63);
  if (lane == 0) nbr_cnt[p] = total < MAXN ? total : MAXN;
}

// ---------------------------------------------------------------------------
// Kernel 2: Q,K,V = x @ {Wq,Wk,Wv}^T in ONE kernel via MFMA 16x16x32 bf16.
// x loaded as f32 and converted to bf16 frags in-register (no staging pass).
// Block = 256 thr = 4 waves; each wave computes 16 rows x 128 cols x 3 mats.
// Fragment layout (m89-verified): A(row,k): lane=row+16*(k>>3), elem=k&7;
// B(col,k): lane=col+16*(k>>3), elem=k&7; D: col=lane&15, row=(lane>>4)*4+r.
__global__ void __launch_bounds__(256, 2)
qkv_kernel(const float* __restrict__ x,
           const unsigned short* __restrict__ Wb,
           float* __restrict__ Qf, float* __restrict__ Kf,
           float* __restrict__ Vf) {
  int tid = threadIdx.x;
  int wv = tid >> 6;
  int lane = tid & 63;
  int lrow = lane & 15;
  int kb = lane >> 4;                    // 0..3
  int row0 = blockIdx.x * 64 + wv * 16;  // wave's 16-row base

  floatx4 acc[3][8];
#pragma unroll
  for (int m = 0; m < 3; ++m)
#pragma unroll
    for (int c = 0; c < 8; ++c) acc[m][c] = (floatx4){0.f, 0.f, 0.f, 0.f};

#pragma unroll
  for (int ks = 0; ks < 4; ++ks) {
    int k0 = ks * 32 + kb * 8;
    // load 8 f32 of x, convert to bf16 frag
    const float4* xr = reinterpret_cast<const float4*>(x + (size_t)(row0 + lrow) * DD + k0);
    float4 x0 = xr[0], x1 = xr[1];
    short8 a;
    a[0] = (short)f2bf(x0.x); a[1] = (short)f2bf(x0.y);
    a[2] = (short)f2bf(x0.z); a[3] = (short)f2bf(x0.w);
    a[4] = (short)f2bf(x1.x); a[5] = (short)f2bf(x1.y);
    a[6] = (short)f2bf(x1.z); a[7] = (short)f2bf(x1.w);
#pragma unroll
    for (int m = 0; m < 3; ++m) {
      const unsigned short* W = Wb + (size_t)m * DD * DD;
#pragma unroll
      for (int c = 0; c < 8; ++c) {
        short8 bf = *reinterpret_cast<const short8*>(W + (size_t)(c * 16 + lrow) * DD + k0);
        acc[m][c] = __builtin_amdgcn_mfma_f32_16x16x32_bf16(a, bf, acc[m][c], 0, 0, 0);
      }
    }
  }
#pragma unroll
  for (int m = 0; m < 3; ++m) {
    float* O = m == 0 ? Qf : (m == 1 ? Kf : Vf);
#pragma unroll
    for (int c = 0; c < 8; ++c)
#pragma unroll
      for (int r = 0; r < 4; ++r)
        O[(size_t)(row0 + kb * 4 + r) * DD + c * 16 + lrow] = acc[m][c][r];
  }
}

// ---------------------------------------------------------------------------
// Kernel 3: fused sparse attention + output projection.
// Block = 256 thr handles RPB=16 consecutive (b,p) rows.
//  B: QK dots    — 16 thr/row sweep (head, neighbor) tasks, scores -> LDS
//  C: softmax    — 1 thr per (row,head), <=17 elems, normalized in LDS
//  D: PV gather  — 16 thr/row, 8 elems each, coalesced V rows; ctx -> LDS bf16
//  E: out-proj   — ctx[16][128] @ Wo^T via MFMA, write f32 out directly
__global__ void attn_out_kernel(const float* __restrict__ Qf,
                                const float* __restrict__ Kf,
                                const float* __restrict__ Vf,
                                const unsigned short* __restrict__ WoB,
                                const int* __restrict__ nbr_idx,
                                const int* __restrict__ nbr_cnt,
                                float* __restrict__ out) {
  __shared__ int idx_s[RPB][MAXN];
  __shared__ int cnt_s[RPB];
  __shared__ float sc_s[RPB][NH][MAXN];
  __shared__ unsigned short ctx_s[RPB][DD];

  int t = threadIdx.x;
  int r0 = blockIdx.x * RPB;
  int b = r0 >> 12;             // RPB divides PP, no straddle
  int bBase = b * PP;

  // load neighbor lists
  if (t < RPB) cnt_s[t] = nbr_cnt[(r0 + t) & (PP - 1)];
  for (int u = t; u < RPB * MAXN; u += 256) {
    int r = u / MAXN, i = u % MAXN;
    idx_s[r][i] = nbr_idx[((r0 + r) & (PP - 1)) * MAXN + i];
  }
  __syncthreads();

  int r = t >> 4, tg = t & 15;
  int cnt = cnt_s[r];
  const float* Qrow = Qf + (size_t)(r0 + r) * DD;

  // phase B: QK dots
#pragma unroll
  for (int h = 0; h < NH; ++h) {
    const float4* Qr = reinterpret_cast<const float4*>(Qrow + h * HDIM);
    for (int i = tg; i < cnt; i += 16) {
      int j = idx_s[r][i];
      const float4* Kr =
          reinterpret_cast<const float4*>(Kf + (size_t)(bBase + j) * DD + h * HDIM);
      float acc = 0.f;
#pragma unroll
      for (int c = 0; c < 8; ++c) {
        float4 q = Qr[c], k = Kr[c];
        acc = fmaf(q.x, k.x, acc);
        acc = fmaf(q.y, k.y, acc);
        acc = fmaf(q.z, k.z, acc);
        acc = fmaf(q.w, k.w, acc);
      }
      sc_s[r][h][i] = acc * 0.17677669529663689f;  // 1/sqrt(32)
    }
  }
  __syncthreads();

  // phase C: per-(row,head) softmax over <=17 scores
  if (t < RPB * NH) {
    int rr = t >> 2, h = t & 3;
    int cn = cnt_s[rr];
    float mx = -1e30f;
    for (int i = 0; i < cn; ++i) mx = fmaxf(mx, sc_s[rr][h][i]);
    float sum = 0.f;
    for (int i = 0; i < cn; ++i) {
      float w = __expf(sc_s[rr][h][i] - mx);
      sc_s[rr][h][i] = w;
      sum += w;
    }
    float inv = 1.f / sum;  // cnt>=1 (diagonal) => sum>=1e-?.. >0
    for (int i = 0; i < cn; ++i) sc_s[rr][h][i] *= inv;
  }
  __syncthreads();

  // phase D: PV gather; ctx -> LDS bf16
  {
    int e0 = tg * 8;
    int h = e0 >> 5;
    float acc[8];
#pragma unroll
    for (int q = 0; q < 8; ++q) acc[q] = 0.f;
    for (int i = 0; i < cnt; ++i) {
      int j = idx_s[r][i];
      float w = sc_s[r][h][i];
      const float4* Vr = reinterpret_cast<const float4*>(Vf + (size_t)(bBase + j) * DD + e0);
      float4 v0 = Vr[0], v1 = Vr[1];
      acc[0] = fmaf(w, v0.x, acc[0]);
      acc[1] = fmaf(w, v0.y, acc[1]);
      acc[2] = fmaf(w, v0.z, acc[2]);
      acc[3] = fmaf(w, v0.w, acc[3]);
      acc[4] = fmaf(w, v1.x, acc[4]);
      acc[5] = fmaf(w, v1.y, acc[5]);
      acc[6] = fmaf(w, v1.z, acc[6]);
      acc[7] = fmaf(w, v1.w, acc[7]);
    }
    short8 cb;
#pragma unroll
    for (int q = 0; q < 8; ++q) cb[q] = (short)f2bf(acc[q]);
    *reinterpret_cast<short8*>(&ctx_s[r][e0]) = cb;
  }
  __syncthreads();

  // phase E: out[16][128] = ctx @ Wo^T via MFMA; wave w does cols [w*32,w*32+32)
  {
    int wv = t >> 6;
    int lane = t & 63;
    int lrow = lane & 15;
    int kb = lane >> 4;
    floatx4 acc2[2];
    acc2[0] = (floatx4){0.f, 0.f, 0.f, 0.f};
    acc2[1] = (floatx4){0.f, 0.f, 0.f, 0.f};
#pragma unroll
    for (int ks = 0; ks < 4; ++ks) {
      int k0 = ks * 32 + kb * 8;
      short8 a = *reinterpret_cast<const short8*>(&ctx_s[lrow][k0]);
#pragma unroll
      for (int c2 = 0; c2 < 2; ++c2) {
        int col_tile = wv * 2 + c2;
        short8 bf = *reinterpret_cast<const short8*>(
            WoB + (size_t)(col_tile * 16 + lrow) * DD + k0);
        acc2[c2] = __builtin_amdgcn_mfma_f32_16x16x32_bf16(a, bf, acc2[c2], 0, 0, 0);
      }
    }
#pragma unroll
    for (int c2 = 0; c2 < 2; ++c2)
#pragma unroll
      for (int rr = 0; rr < 4; ++rr)
        out[(size_t)(r0 + kb * 4 + rr) * DD + (wv * 2 + c2) * 16 + lrow] = acc2[c2][rr];
  }
}

// ---------------------------------------------------------------------------
extern "C" void kernel_launch(void* const* d_in, const int* in_sizes, int n_in,
                              void* d_out, int out_size, void* d_ws, size_t ws_size,
                              hipStream_t stream) {
  const float* x    = (const float*)d_in[0];
  const float* Wq   = (const float*)d_in[1];
  const float* Wk   = (const float*)d_in[2];
  const float* Wv   = (const float*)d_in[3];
  const float* Wo   = (const float*)d_in[4];
  const void*  mask = d_in[5];
  float* out = (float*)d_out;

  char* ws = (char*)d_ws;
  int* nbr_cnt = (int*)(ws + 0);                        //   16 KB
  int* nbr_idx = (int*)(ws + 16384);                    //  384 KB -> 409600
  unsigned short* Wb = (unsigned short*)(ws + 409600);  //  128 KB -> 540672
  float* Qf = (float*)(ws + 540672);                    //    4 MB -> 4734976
  float* Kf = (float*)(ws + 4734976);                   //    4 MB -> 8929280
  float* Vf = (float*)(ws + 8929280);                   //    4 MB -> 13123584

  compact_kernel<<<PP, 64, 0, stream>>>(mask, (const float4*)Wq, (const float4*)Wk,
                                        (const float4*)Wv, (const float4*)Wo,
                                        nbr_idx, nbr_cnt, Wb);
  qkv_kernel<<<MROWS / 64, 256, 0, stream>>>(x, Wb, Qf, Kf, Vf);
  attn_out_kernel<<<MROWS / RPB, 256, 0, stream>>>(
      Qf, Kf, Vf, Wb + (size_t)3 * DD * DD, nbr_idx, nbr_cnt, out);
}

// Round 5
// 54.056 us; speedup vs baseline: 1.2211x; 1.2211x over previous
//
#include <hip/hip_runtime.h>
#include <hip/hip_bf16.h>

// Problem constants
#define PP     4096      // P assets
#define BB     2         // batch
#define DD     128       // model dim
#define NH     4         // heads
#define HDIM   32        // head dim
#define MROWS  8192      // B*P
#define MAXN   24        // max neighbors kept (true max is 17)

typedef __attribute__((ext_vector_type(8))) short short8;   // 8 bf16 = 4 VGPR
typedef __attribute__((ext_vector_type(4))) float floatx4;  // MFMA acc

__device__ __forceinline__ unsigned short f2bf(float f) {
  __hip_bfloat16 h = __float2bfloat16(f);
  return *reinterpret_cast<unsigned short*>(&h);
}

// ---------------------------------------------------------------------------
// Mask dtype detection (0 = u8/bool, 1 = int32, 2 = float32) — see round 1.
__device__ __forceinline__ int detect_mode(const unsigned char* mask) {
  bool u8ok = true, f32ok = true;
#pragma unroll
  for (int p = 1; p <= 3; ++p) {
    size_t f = (size_t)p * PP + p;
    u8ok = u8ok && (mask[f] == 1);
    unsigned int dw = reinterpret_cast<const unsigned int*>(mask)[f];
    f32ok = f32ok && (dw == 0x3f800000u);
  }
  return u8ok ? 0 : (f32ok ? 2 : 1);
}

// ---------------------------------------------------------------------------
// Kernel 1: compact one mask row per block (64 threads = 1 wave).
// Blocks 0..255 additionally convert the 4 weight matrices to bf16.
__global__ void compact_kernel(const void* __restrict__ mask,
                               const float4* __restrict__ Wq,
                               const float4* __restrict__ Wk,
                               const float4* __restrict__ Wv,
                               const float4* __restrict__ Wo,
                               int* __restrict__ nbr_idx,
                               int* __restrict__ nbr_cnt,
                               unsigned short* __restrict__ Wb) {
  int p = blockIdx.x;
  int lane = threadIdx.x;  // 0..63

  if (p < 256) {  // weight conversion: 16384 float4 units total
    int u = p * 64 + lane;
    int m = u >> 12, off = u & 4095;
    const float4* Ws = m == 0 ? Wq : (m == 1 ? Wk : (m == 2 ? Wv : Wo));
    float4 v = Ws[off];
    ushort4 o;
    o.x = f2bf(v.x); o.y = f2bf(v.y); o.z = f2bf(v.z); o.w = f2bf(v.w);
    *reinterpret_cast<ushort4*>(Wb + (size_t)m * DD * DD + (size_t)off * 4) = o;
  }

  int md = detect_mode((const unsigned char*)mask);
  unsigned long long bits = 0ULL;  // bit i => column lane*64+i is a neighbor

  if (md == 0) {
    const uint4* base =
        reinterpret_cast<const uint4*>((const unsigned char*)mask + (size_t)p * PP) +
        lane * 4;
#pragma unroll
    for (int c = 0; c < 4; ++c) {
      uint4 v = base[c];
      unsigned int w4[4] = {v.x, v.y, v.z, v.w};
#pragma unroll
      for (int wi = 0; wi < 4; ++wi) {
        unsigned int w = w4[wi];
        unsigned int nz = ((((w & 0x7F7F7F7Fu) + 0x7F7F7F7Fu) | w) & 0x80808080u);
        unsigned int x = (nz >> 7) & 0x01010101u;
        unsigned int b4 = (x | (x >> 7) | (x >> 14) | (x >> 21)) & 0xFu;
        bits |= (unsigned long long)b4 << (c * 16 + wi * 4);
      }
    }
  } else if (md == 1) {
    const uint4* base =
        reinterpret_cast<const uint4*>((const int*)mask + (size_t)p * PP) + lane * 16;
#pragma unroll
    for (int c = 0; c < 16; ++c) {
      uint4 v = base[c];
      unsigned long long b = (v.x ? 1u : 0u) | (v.y ? 2u : 0u) |
                             (v.z ? 4u : 0u) | (v.w ? 8u : 0u);
      bits |= b << (c * 4);
    }
  } else {
    const float4* base =
        reinterpret_cast<const float4*>((const float*)mask + (size_t)p * PP) + lane * 16;
#pragma unroll
    for (int c = 0; c < 16; ++c) {
      float4 v = base[c];
      unsigned long long b = (v.x != 0.f ? 1u : 0u) | (v.y != 0.f ? 2u : 0u) |
                             (v.z != 0.f ? 4u : 0u) | (v.w != 0.f ? 8u : 0u);
      bits |= b << (c * 4);
    }
  }

  int cnt = __popcll(bits);
  int pre = cnt;
#pragma unroll
  for (int d = 1; d < 64; d <<= 1) {
    int t = __shfl_up(pre, d);
    if (lane >= d) pre += t;
  }
  int base_pos = pre - cnt;  // exclusive prefix
  unsigned long long m = bits;
  while (m) {
    int b = __ffsll((long long)m) - 1;
    m &= m - 1;
    if (base_pos < MAXN) nbr_idx[p * MAXN + base_pos] = lane * 64 + b;
    ++base_pos;
  }
  int total = __shfl(pre, 63);
  if (lane == 0) nbr_cnt[p] = total < MAXN ? total : MAXN;
}

// ---------------------------------------------------------------------------
// Kernel 2: Q,K,V = x @ {Wq,Wk,Wv}^T via MFMA 16x16x32 bf16.
// Grid 512 blocks; block = 4 waves handles 16 rows; wave wv computes cols
// [wv*32, wv*32+32) for all 3 mats (24 MFMA). A-frags identical across waves
// (L1 broadcast). Fragment layout m89-verified.
__global__ void qkv_kernel(const float* __restrict__ x,
                           const unsigned short* __restrict__ Wb,
                           float* __restrict__ Qf, float* __restrict__ Kf,
                           float* __restrict__ Vf) {
  int tid = threadIdx.x;
  int wv = tid >> 6;
  int lane = tid & 63;
  int lrow = lane & 15;
  int kb = lane >> 4;                 // 0..3
  int row0 = blockIdx.x * 16;

  floatx4 acc[3][2];
#pragma unroll
  for (int m = 0; m < 3; ++m)
#pragma unroll
    for (int c = 0; c < 2; ++c) acc[m][c] = (floatx4){0.f, 0.f, 0.f, 0.f};

#pragma unroll
  for (int ks = 0; ks < 4; ++ks) {
    int k0 = ks * 32 + kb * 8;
    const float4* xr = reinterpret_cast<const float4*>(x + (size_t)(row0 + lrow) * DD + k0);
    float4 x0 = xr[0], x1 = xr[1];
    short8 a;
    a[0] = (short)f2bf(x0.x); a[1] = (short)f2bf(x0.y);
    a[2] = (short)f2bf(x0.z); a[3] = (short)f2bf(x0.w);
    a[4] = (short)f2bf(x1.x); a[5] = (short)f2bf(x1.y);
    a[6] = (short)f2bf(x1.z); a[7] = (short)f2bf(x1.w);
#pragma unroll
    for (int m = 0; m < 3; ++m) {
      const unsigned short* W = Wb + (size_t)m * DD * DD;
#pragma unroll
      for (int c = 0; c < 2; ++c) {
        int col_tile = wv * 2 + c;
        short8 bf = *reinterpret_cast<const short8*>(
            W + (size_t)(col_tile * 16 + lrow) * DD + k0);
        acc[m][c] = __builtin_amdgcn_mfma_f32_16x16x32_bf16(a, bf, acc[m][c], 0, 0, 0);
      }
    }
  }
#pragma unroll
  for (int m = 0; m < 3; ++m) {
    float* O = m == 0 ? Qf : (m == 1 ? Kf : Vf);
#pragma unroll
    for (int c = 0; c < 2; ++c)
#pragma unroll
      for (int r = 0; r < 4; ++r)
        O[(size_t)(row0 + kb * 4 + r) * DD + (wv * 2 + c) * 16 + lrow] = acc[m][c][r];
  }
}

// ---------------------------------------------------------------------------
// Kernel 3: sparse attention, shuffle-softmax. Block = 256 thr = 2 rows;
// per row 128 thr: h = (sub>>5), il = sub&31.
// Phase 1: lane (h,il) = whole dot for neighbor il (serial 32 FMA, no shfl).
// Softmax = 10 shuffles within aligned 32-lane groups. Phase 2: coalesced PV.
__global__ void attn_kernel(const float* __restrict__ Qf,
                            const float* __restrict__ Kf,
                            const float* __restrict__ Vf,
                            const int* __restrict__ nbr_idx,
                            const int* __restrict__ nbr_cnt,
                            unsigned short* __restrict__ ctxb) {
  int tid = threadIdx.x;
  int r = tid >> 7;                    // 0..1
  int sub = tid & 127;
  int h = sub >> 5, il = sub & 31;
  int row = blockIdx.x * 2 + r;        // global (b,p) row; 2 | 4096 => no straddle
  int b = row >> 12, p = row & (PP - 1);
  int bBase = b * PP;

  __shared__ int idx_s[2][MAXN];
  __shared__ int cnt_s[2];
  if (tid < 2) cnt_s[tid] = nbr_cnt[(blockIdx.x * 2 + tid) & (PP - 1)];
  if (tid >= 128 && tid < 128 + 2 * MAXN) {
    int u = tid - 128;
    idx_s[u / MAXN][u % MAXN] = nbr_idx[((blockIdx.x * 2 + u / MAXN) & (PP - 1)) * MAXN + u % MAXN];
  }
  __syncthreads();
  int cnt = cnt_s[r];

  // phase 1: il = neighbor index
  float s = -1e30f;
  if (il < cnt) {
    int j = idx_s[r][il];
    const float4* Qr = reinterpret_cast<const float4*>(Qf + (size_t)row * DD + h * HDIM);
    const float4* Kr =
        reinterpret_cast<const float4*>(Kf + (size_t)(bBase + j) * DD + h * HDIM);
    float acc = 0.f;
#pragma unroll
    for (int c = 0; c < 8; ++c) {
      float4 q = Qr[c], k = Kr[c];
      acc = fmaf(q.x, k.x, acc);
      acc = fmaf(q.y, k.y, acc);
      acc = fmaf(q.z, k.z, acc);
      acc = fmaf(q.w, k.w, acc);
    }
    s = acc * 0.17677669529663689f;  // 1/sqrt(32)
  }
  float mx = s;
  mx = fmaxf(mx, __shfl_xor(mx, 16));
  mx = fmaxf(mx, __shfl_xor(mx, 8));
  mx = fmaxf(mx, __shfl_xor(mx, 4));
  mx = fmaxf(mx, __shfl_xor(mx, 2));
  mx = fmaxf(mx, __shfl_xor(mx, 1));
  float w = (il < cnt) ? __expf(s - mx) : 0.f;
  float l = w;
  l += __shfl_xor(l, 16);
  l += __shfl_xor(l, 8);
  l += __shfl_xor(l, 4);
  l += __shfl_xor(l, 2);
  l += __shfl_xor(l, 1);
  __shared__ float ws_s[2][NH][32];
  ws_s[r][h][il] = w / l;  // cnt>=1 (diagonal) => l>0
  __syncthreads();

  // phase 2: il = element e (coalesced V reads)
  float acc = 0.f;
  for (int i = 0; i < cnt; ++i) {
    int j = idx_s[r][i];
    acc = fmaf(ws_s[r][h][i], Vf[(size_t)(bBase + j) * DD + h * HDIM + il], acc);
  }
  ctxb[(size_t)row * DD + h * HDIM + il] = f2bf(acc);
}

// ---------------------------------------------------------------------------
// Kernel 4: out = ctx @ Wo^T via MFMA. Grid 512 blocks; block = 4 waves
// handles 16 rows; wave wv covers cols [wv*32, wv*32+32) (8 MFMA).
__global__ void oproj_kernel(const unsigned short* __restrict__ ctxb,
                             const unsigned short* __restrict__ WoB,
                             float* __restrict__ out) {
  int tid = threadIdx.x;
  int wv = tid >> 6;
  int lane = tid & 63;
  int lrow = lane & 15;
  int kb = lane >> 4;
  int row0 = blockIdx.x * 16;

  floatx4 acc[2];
  acc[0] = (floatx4){0.f, 0.f, 0.f, 0.f};
  acc[1] = (floatx4){0.f, 0.f, 0.f, 0.f};
#pragma unroll
  for (int ks = 0; ks < 4; ++ks) {
    int k0 = ks * 32 + kb * 8;
    short8 a = *reinterpret_cast<const short8*>(ctxb + (size_t)(row0 + lrow) * DD + k0);
#pragma unroll
    for (int c = 0; c < 2; ++c) {
      int col_tile = wv * 2 + c;
      short8 bf = *reinterpret_cast<const short8*>(
          WoB + (size_t)(col_tile * 16 + lrow) * DD + k0);
      acc[c] = __builtin_amdgcn_mfma_f32_16x16x32_bf16(a, bf, acc[c], 0, 0, 0);
    }
  }
#pragma unroll
  for (int c = 0; c < 2; ++c)
#pragma unroll
    for (int r = 0; r < 4; ++r)
      out[(size_t)(row0 + kb * 4 + r) * DD + (wv * 2 + c) * 16 + lrow] = acc[c][r];
}

// ---------------------------------------------------------------------------
extern "C" void kernel_launch(void* const* d_in, const int* in_sizes, int n_in,
                              void* d_out, int out_size, void* d_ws, size_t ws_size,
                              hipStream_t stream) {
  const float* x    = (const float*)d_in[0];
  const float* Wq   = (const float*)d_in[1];
  const float* Wk   = (const float*)d_in[2];
  const float* Wv   = (const float*)d_in[3];
  const float* Wo   = (const float*)d_in[4];
  const void*  mask = d_in[5];
  float* out = (float*)d_out;

  char* ws = (char*)d_ws;
  int* nbr_cnt = (int*)(ws + 0);                        //   16 KB
  int* nbr_idx = (int*)(ws + 16384);                    //  384 KB -> 409600
  unsigned short* Wb = (unsigned short*)(ws + 409600);  //  128 KB -> 540672
  float* Qf = (float*)(ws + 540672);                    //    4 MB -> 4734976
  float* Kf = (float*)(ws + 4734976);                   //    4 MB -> 8929280
  float* Vf = (float*)(ws + 8929280);                   //    4 MB -> 13123584
  unsigned short* ctxb = (unsigned short*)(ws + 13123584); // 2 MB -> 15220736

  compact_kernel<<<PP, 64, 0, stream>>>(mask, (const float4*)Wq, (const float4*)Wk,
                                        (const float4*)Wv, (const float4*)Wo,
                                        nbr_idx, nbr_cnt, Wb);
  qkv_kernel<<<MROWS / 16, 256, 0, stream>>>(x, Wb, Qf, Kf, Vf);
  attn_kernel<<<MROWS / 2, 256, 0, stream>>>(Qf, Kf, Vf, nbr_idx, nbr_cnt, ctxb);
  oproj_kernel<<<MROWS / 16, 256, 0, stream>>>(ctxb, Wb + (size_t)3 * DD * DD, out);
}

// Round 6
// 46.752 us; speedup vs baseline: 1.4119x; 1.1562x over previous
//
#include <hip/hip_runtime.h>
#include <hip/hip_bf16.h>

// Problem constants
#define PP     4096      // P assets
#define BB     2         // batch
#define DD     128       // model dim
#define NH     4         // heads
#define HDIM   32        // head dim
#define MROWS  8192      // B*P
#define MAXN   24        // max neighbors kept (true max is 17)

typedef __attribute__((ext_vector_type(8))) short short8;   // 8 bf16 = 4 VGPR
typedef __attribute__((ext_vector_type(4))) float floatx4;  // MFMA acc

__device__ __forceinline__ unsigned short f2bf(float f) {
  __hip_bfloat16 h = __float2bfloat16(f);
  return *reinterpret_cast<unsigned short*>(&h);
}
__device__ __forceinline__ float bf2f(unsigned short u) {
  union { unsigned int i; float f; } c;
  c.i = ((unsigned int)u) << 16;
  return c.f;
}

// ---------------------------------------------------------------------------
// Mask dtype detection (0 = u8/bool, 1/2 = 4-byte int/float) — see round 1.
// For 4-byte encodings, dword != 0 <=> element true (mask holds 0/1 values),
// so modes 1 and 2 share a path.
__device__ __forceinline__ int detect_mode(const unsigned char* mask) {
  bool u8ok = true;
#pragma unroll
  for (int p = 1; p <= 3; ++p) {
    size_t f = (size_t)p * PP + p;
    u8ok = u8ok && (mask[f] == 1);
  }
  return u8ok ? 0 : 1;
}

// ---------------------------------------------------------------------------
// Kernel 1: compact one mask row per block (256 threads = 4 waves).
// Thread t covers row elements [t*16, t*16+16) -> 16-bit local hit mask;
// wave shfl prefix + LDS cross-wave merge orders the scatter. Slots
// [cnt, MAXN) are padded with p (self) so downstream loops are fixed-trip.
// Blocks 0..63 additionally convert the 4 weight matrices to bf16.
__global__ void compact_kernel(const void* __restrict__ mask,
                               const float4* __restrict__ Wq,
                               const float4* __restrict__ Wk,
                               const float4* __restrict__ Wv,
                               const float4* __restrict__ Wo,
                               int* __restrict__ nbr_idx,
                               int* __restrict__ nbr_cnt,
                               unsigned short* __restrict__ Wb) {
  int p = blockIdx.x;
  int t = threadIdx.x;   // 0..255
  int lane = t & 63, wv = t >> 6;

  if (p < 64) {  // weight conversion: 16384 float4 units total
    int u = p * 256 + t;
    int m = u >> 12, off = u & 4095;
    const float4* Ws = m == 0 ? Wq : (m == 1 ? Wk : (m == 2 ? Wv : Wo));
    float4 v = Ws[off];
    ushort4 o;
    o.x = f2bf(v.x); o.y = f2bf(v.y); o.z = f2bf(v.z); o.w = f2bf(v.w);
    *reinterpret_cast<ushort4*>(Wb + (size_t)m * DD * DD + (size_t)off * 4) = o;
  }

  int md = detect_mode((const unsigned char*)mask);
  unsigned int bits = 0;  // bit i => column t*16+i is a neighbor

  if (md == 0) {
    uint4 v = reinterpret_cast<const uint4*>((const unsigned char*)mask +
                                             (size_t)p * PP)[t];
    unsigned int w4[4] = {v.x, v.y, v.z, v.w};
#pragma unroll
    for (int wi = 0; wi < 4; ++wi) {
      unsigned int w = w4[wi];
      unsigned int nz = ((((w & 0x7F7F7F7Fu) + 0x7F7F7F7Fu) | w) & 0x80808080u);
      unsigned int x = (nz >> 7) & 0x01010101u;
      unsigned int b4 = (x | (x >> 7) | (x >> 14) | (x >> 21)) & 0xFu;
      bits |= b4 << (wi * 4);
    }
  } else {
    const uint4* base =
        reinterpret_cast<const uint4*>((const unsigned int*)mask + (size_t)p * PP) +
        t * 4;
#pragma unroll
    for (int c = 0; c < 4; ++c) {
      uint4 v = base[c];
      unsigned int b4 = (v.x ? 1u : 0u) | (v.y ? 2u : 0u) |
                        (v.z ? 4u : 0u) | (v.w ? 8u : 0u);
      bits |= b4 << (c * 4);
    }
  }

  int cnt = __popc(bits);
  int pre = cnt;  // inclusive prefix within wave
#pragma unroll
  for (int d = 1; d < 64; d <<= 1) {
    int tt = __shfl_up(pre, d);
    if (lane >= d) pre += tt;
  }
  __shared__ int wsum[4];
  if (lane == 63) wsum[wv] = pre;
  __syncthreads();
  int woff = 0;
#pragma unroll
  for (int w = 0; w < 4; ++w)
    if (w < wv) woff += wsum[w];
  int base_pos = woff + pre - cnt;  // exclusive global prefix
  unsigned int m = bits;
  while (m) {
    int b = __ffs(m) - 1;
    m &= m - 1;
    if (base_pos < MAXN) nbr_idx[p * MAXN + base_pos] = t * 16 + b;
    ++base_pos;
  }
  int total = wsum[0] + wsum[1] + wsum[2] + wsum[3];
  int cl = total < MAXN ? total : MAXN;
  if (t == 0) nbr_cnt[p] = cl;
  if (t >= cl && t < MAXN) nbr_idx[p * MAXN + t] = p;  // pad with self
}

// ---------------------------------------------------------------------------
// Kernel 2: Q,K,V = x @ {Wq,Wk,Wv}^T via MFMA 16x16x32 bf16.
// Grid 512 blocks; block = 4 waves handles 16 rows; wave wv computes cols
// [wv*32, wv*32+32) for all 3 mats (24 MFMA). Q written f32; K,V bf16.
// Fragment layout (m89-verified): A(row,k): lane=row+16*(k>>3), elem=k&7;
// B(col,k): lane=col+16*(k>>3), elem=k&7; D: col=lane&15, row=(lane>>4)*4+r.
__global__ void qkv_kernel(const float* __restrict__ x,
                           const unsigned short* __restrict__ Wb,
                           float* __restrict__ Qf,
                           unsigned short* __restrict__ Kb,
                           unsigned short* __restrict__ Vb) {
  int tid = threadIdx.x;
  int wv = tid >> 6;
  int lane = tid & 63;
  int lrow = lane & 15;
  int kb = lane >> 4;                 // 0..3
  int row0 = blockIdx.x * 16;

  floatx4 acc[3][2];
#pragma unroll
  for (int m = 0; m < 3; ++m)
#pragma unroll
    for (int c = 0; c < 2; ++c) acc[m][c] = (floatx4){0.f, 0.f, 0.f, 0.f};

#pragma unroll
  for (int ks = 0; ks < 4; ++ks) {
    int k0 = ks * 32 + kb * 8;
    const float4* xr = reinterpret_cast<const float4*>(x + (size_t)(row0 + lrow) * DD + k0);
    float4 x0 = xr[0], x1 = xr[1];
    short8 a;
    a[0] = (short)f2bf(x0.x); a[1] = (short)f2bf(x0.y);
    a[2] = (short)f2bf(x0.z); a[3] = (short)f2bf(x0.w);
    a[4] = (short)f2bf(x1.x); a[5] = (short)f2bf(x1.y);
    a[6] = (short)f2bf(x1.z); a[7] = (short)f2bf(x1.w);
#pragma unroll
    for (int m = 0; m < 3; ++m) {
      const unsigned short* W = Wb + (size_t)m * DD * DD;
#pragma unroll
      for (int c = 0; c < 2; ++c) {
        int col_tile = wv * 2 + c;
        short8 bf = *reinterpret_cast<const short8*>(
            W + (size_t)(col_tile * 16 + lrow) * DD + k0);
        acc[m][c] = __builtin_amdgcn_mfma_f32_16x16x32_bf16(a, bf, acc[m][c], 0, 0, 0);
      }
    }
  }
#pragma unroll
  for (int c = 0; c < 2; ++c)
#pragma unroll
    for (int r = 0; r < 4; ++r) {
      size_t off = (size_t)(row0 + kb * 4 + r) * DD + (wv * 2 + c) * 16 + lrow;
      Qf[off] = acc[0][c][r];
      Kb[off] = f2bf(acc[1][c][r]);
      Vb[off] = f2bf(acc[2][c][r]);
    }
}

// ---------------------------------------------------------------------------
// Kernel 3: sparse attention. Block = 256 thr = 2 rows; per row 128 thr:
// h = (sub>>5), il = sub&31.
// Phase 1: lane (h,il) = whole bf16-K dot for neighbor slot il (4 gather
// loads, unconditional via clamped slot). Softmax = 10 shuffles.
// Phase 2: fixed MAXN-trip unrolled PV gather (padded idx, zero weights).
__global__ void attn_kernel(const float* __restrict__ Qf,
                            const unsigned short* __restrict__ Kb,
                            const unsigned short* __restrict__ Vb,
                            const int* __restrict__ nbr_idx,
                            const int* __restrict__ nbr_cnt,
                            unsigned short* __restrict__ ctxb) {
  int tid = threadIdx.x;
  int r = tid >> 7;                    // 0..1
  int sub = tid & 127;
  int h = sub >> 5, il = sub & 31;
  int row = blockIdx.x * 2 + r;        // 2 | 4096 => no batch straddle
  int b = row >> 12;
  int bBase = b * PP;

  __shared__ int idx_s[2][MAXN];
  __shared__ int cnt_s[2];
  __shared__ float ws_s[2][NH][32];
  if (tid < 2) cnt_s[tid] = nbr_cnt[(blockIdx.x * 2 + tid) & (PP - 1)];
  if (tid >= 128 && tid < 128 + 2 * MAXN) {
    int u = tid - 128;
    idx_s[u / MAXN][u % MAXN] =
        nbr_idx[((blockIdx.x * 2 + u / MAXN) & (PP - 1)) * MAXN + u % MAXN];
  }
  __syncthreads();
  int cnt = cnt_s[r];

  // phase 1: il = neighbor slot (clamped; loads unconditional, score masked)
  int slot = il < MAXN ? il : MAXN - 1;
  int j = idx_s[r][slot];
  const unsigned short* Kr = Kb + (size_t)(bBase + j) * DD + h * HDIM;
  const float4* Qr = reinterpret_cast<const float4*>(Qf + (size_t)row * DD + h * HDIM);
  float acc = 0.f;
#pragma unroll
  for (int c = 0; c < 4; ++c) {
    short8 kk = *reinterpret_cast<const short8*>(Kr + c * 8);
    float4 q0 = Qr[c * 2], q1 = Qr[c * 2 + 1];
    acc = fmaf(q0.x, bf2f((unsigned short)kk[0]), acc);
    acc = fmaf(q0.y, bf2f((unsigned short)kk[1]), acc);
    acc = fmaf(q0.z, bf2f((unsigned short)kk[2]), acc);
    acc = fmaf(q0.w, bf2f((unsigned short)kk[3]), acc);
    acc = fmaf(q1.x, bf2f((unsigned short)kk[4]), acc);
    acc = fmaf(q1.y, bf2f((unsigned short)kk[5]), acc);
    acc = fmaf(q1.z, bf2f((unsigned short)kk[6]), acc);
    acc = fmaf(q1.w, bf2f((unsigned short)kk[7]), acc);
  }
  float s = (il < cnt) ? acc * 0.17677669529663689f : -1e30f;  // 1/sqrt(32)

  float mx = s;
  mx = fmaxf(mx, __shfl_xor(mx, 16));
  mx = fmaxf(mx, __shfl_xor(mx, 8));
  mx = fmaxf(mx, __shfl_xor(mx, 4));
  mx = fmaxf(mx, __shfl_xor(mx, 2));
  mx = fmaxf(mx, __shfl_xor(mx, 1));
  float w = (il < cnt) ? __expf(s - mx) : 0.f;
  float l = w;
  l += __shfl_xor(l, 16);
  l += __shfl_xor(l, 8);
  l += __shfl_xor(l, 4);
  l += __shfl_xor(l, 2);
  l += __shfl_xor(l, 1);
  ws_s[r][h][il] = w / l;  // cnt>=1 (diagonal) => l>0
  __syncthreads();

  // phase 2: il = element e; fixed-trip, all loads independent
  float acc2 = 0.f;
#pragma unroll
  for (int i = 0; i < MAXN; ++i) {
    int jj = idx_s[r][i];
    float wgt = ws_s[r][h][i];
    acc2 = fmaf(wgt, bf2f(Vb[(size_t)(bBase + jj) * DD + h * HDIM + il]), acc2);
  }
  ctxb[(size_t)row * DD + h * HDIM + il] = f2bf(acc2);
}

// ---------------------------------------------------------------------------
// Kernel 4: out = ctx @ Wo^T via MFMA. Grid 512 blocks; block = 4 waves
// handles 16 rows; wave wv covers cols [wv*32, wv*32+32) (8 MFMA).
__global__ void oproj_kernel(const unsigned short* __restrict__ ctxb,
                             const unsigned short* __restrict__ WoB,
                             float* __restrict__ out) {
  int tid = threadIdx.x;
  int wv = tid >> 6;
  int lane = tid & 63;
  int lrow = lane & 15;
  int kb = lane >> 4;
  int row0 = blockIdx.x * 16;

  floatx4 acc[2];
  acc[0] = (floatx4){0.f, 0.f, 0.f, 0.f};
  acc[1] = (floatx4){0.f, 0.f, 0.f, 0.f};
#pragma unroll
  for (int ks = 0; ks < 4; ++ks) {
    int k0 = ks * 32 + kb * 8;
    short8 a = *reinterpret_cast<const short8*>(ctxb + (size_t)(row0 + lrow) * DD + k0);
#pragma unroll
    for (int c = 0; c < 2; ++c) {
      int col_tile = wv * 2 + c;
      short8 bf = *reinterpret_cast<const short8*>(
          WoB + (size_t)(col_tile * 16 + lrow) * DD + k0);
      acc[c] = __builtin_amdgcn_mfma_f32_16x16x32_bf16(a, bf, acc[c], 0, 0, 0);
    }
  }
#pragma unroll
  for (int c = 0; c < 2; ++c)
#pragma unroll
    for (int r = 0; r < 4; ++r)
      out[(size_t)(row0 + kb * 4 + r) * DD + (wv * 2 + c) * 16 + lrow] = acc[c][r];
}

// ---------------------------------------------------------------------------
extern "C" void kernel_launch(void* const* d_in, const int* in_sizes, int n_in,
                              void* d_out, int out_size, void* d_ws, size_t ws_size,
                              hipStream_t stream) {
  const float* x    = (const float*)d_in[0];
  const float* Wq   = (const float*)d_in[1];
  const float* Wk   = (const float*)d_in[2];
  const float* Wv   = (const float*)d_in[3];
  const float* Wo   = (const float*)d_in[4];
  const void*  mask = d_in[5];
  float* out = (float*)d_out;

  char* ws = (char*)d_ws;
  int* nbr_cnt = (int*)(ws + 0);                        //   16 KB
  int* nbr_idx = (int*)(ws + 16384);                    //  384 KB -> 409600
  unsigned short* Wb = (unsigned short*)(ws + 409600);  //  128 KB -> 540672
  float* Qf = (float*)(ws + 540672);                    //    4 MB -> 4734976
  unsigned short* Kb = (unsigned short*)(ws + 4734976); //    2 MB -> 6832128
  unsigned short* Vb = (unsigned short*)(ws + 6832128); //    2 MB -> 8929280
  unsigned short* ctxb = (unsigned short*)(ws + 8929280); //  2 MB -> 11026432

  compact_kernel<<<PP, 256, 0, stream>>>(mask, (const float4*)Wq, (const float4*)Wk,
                                         (const float4*)Wv, (const float4*)Wo,
                                         nbr_idx, nbr_cnt, Wb);
  qkv_kernel<<<MROWS / 16, 256, 0, stream>>>(x, Wb, Qf, Kb, Vb);
  attn_kernel<<<MROWS / 2, 256, 0, stream>>>(Qf, Kb, Vb, nbr_idx, nbr_cnt, ctxb);
  oproj_kernel<<<MROWS / 16, 256, 0, stream>>>(ctxb, Wb + (size_t)3 * DD * DD, out);
}

// Round 7
// 45.917 us; speedup vs baseline: 1.4375x; 1.0182x over previous
//
#include <hip/hip_runtime.h>
#include <hip/hip_bf16.h>

// Problem constants
#define PP     4096      // P assets
#define BB     2         // batch
#define DD     128       // model dim
#define NH     4         // heads
#define HDIM   32        // head dim
#define MROWS  8192      // B*P
#define MAXN   24        // max neighbors kept (true max is 17)
#define QKVB   512       // qkv tile blocks in fused kernel (MROWS/16)

typedef __attribute__((ext_vector_type(8))) short short8;   // 8 bf16 = 4 VGPR
typedef __attribute__((ext_vector_type(4))) float floatx4;  // MFMA acc

__device__ __forceinline__ unsigned short f2bf(float f) {
  __hip_bfloat16 h = __float2bfloat16(f);
  return *reinterpret_cast<unsigned short*>(&h);
}
__device__ __forceinline__ float bf2f(unsigned short u) {
  union { unsigned int i; float f; } c;
  c.i = ((unsigned int)u) << 16;
  return c.f;
}

// Load 8 consecutive f32 and convert to a bf16 short8 fragment.
__device__ __forceinline__ short8 load_frag_f32(const float* p) {
  const float4* p4 = reinterpret_cast<const float4*>(p);
  float4 a = p4[0], b = p4[1];
  short8 r;
  r[0] = (short)f2bf(a.x); r[1] = (short)f2bf(a.y);
  r[2] = (short)f2bf(a.z); r[3] = (short)f2bf(a.w);
  r[4] = (short)f2bf(b.x); r[5] = (short)f2bf(b.y);
  r[6] = (short)f2bf(b.z); r[7] = (short)f2bf(b.w);
  return r;
}

// Mask dtype detection (0 = u8/bool, 1 = 4-byte int/float; for 4-byte
// encodings dword!=0 <=> true, so int32 and f32 share a path).
__device__ __forceinline__ int detect_mode(const unsigned char* mask) {
  bool u8ok = true;
#pragma unroll
  for (int p = 1; p <= 3; ++p) {
    size_t f = (size_t)p * PP + p;
    u8ok = u8ok && (mask[f] == 1);
  }
  return u8ok ? 0 : 1;
}

// ---------------------------------------------------------------------------
// Kernel 1 (fused): blocks [0, QKVB) compute a 16-row QKV MFMA tile;
// blocks [QKVB, QKVB+PP) compact one mask row each. The 64 MB (or 16 MB)
// mask stream overlaps the GEMM instead of serializing in front of it.
__global__ void fused_compact_qkv(const void* __restrict__ mask,
                                  const float* __restrict__ x,
                                  const float* __restrict__ Wq,
                                  const float* __restrict__ Wk,
                                  const float* __restrict__ Wv,
                                  int* __restrict__ nbr_idx,
                                  int* __restrict__ nbr_cnt,
                                  float* __restrict__ Qf,
                                  unsigned short* __restrict__ Kb,
                                  unsigned short* __restrict__ Vb) {
  int t = threadIdx.x;   // 0..255
  int lane = t & 63, wv = t >> 6;

  if (blockIdx.x < QKVB) {
    // ---- QKV tile: 16 rows; wave wv covers cols [wv*32, wv*32+32) of 3 mats.
    // Fragment layout (m89-verified): A(row,k): lane=row+16*(k>>3), elem=k&7;
    // B(col,k): lane=col+16*(k>>3), elem=k&7; D: col=lane&15, row=(lane>>4)*4+r.
    int lrow = lane & 15;
    int kb = lane >> 4;                 // 0..3
    int row0 = blockIdx.x * 16;

    floatx4 acc[3][2];
#pragma unroll
    for (int m = 0; m < 3; ++m)
#pragma unroll
      for (int c = 0; c < 2; ++c) acc[m][c] = (floatx4){0.f, 0.f, 0.f, 0.f};

#pragma unroll
    for (int ks = 0; ks < 4; ++ks) {
      int k0 = ks * 32 + kb * 8;
      short8 a = load_frag_f32(x + (size_t)(row0 + lrow) * DD + k0);
#pragma unroll
      for (int m = 0; m < 3; ++m) {
        const float* W = m == 0 ? Wq : (m == 1 ? Wk : Wv);
#pragma unroll
        for (int c = 0; c < 2; ++c) {
          int col_tile = wv * 2 + c;
          short8 bf = load_frag_f32(W + (size_t)(col_tile * 16 + lrow) * DD + k0);
          acc[m][c] = __builtin_amdgcn_mfma_f32_16x16x32_bf16(a, bf, acc[m][c], 0, 0, 0);
        }
      }
    }
#pragma unroll
    for (int c = 0; c < 2; ++c)
#pragma unroll
      for (int r = 0; r < 4; ++r) {
        size_t off = (size_t)(row0 + kb * 4 + r) * DD + (wv * 2 + c) * 16 + lrow;
        Qf[off] = acc[0][c][r];
        Kb[off] = f2bf(acc[1][c][r]);
        Vb[off] = f2bf(acc[2][c][r]);
      }
    return;
  }

  // ---- compact: one mask row per block (4 waves). Thread t covers elements
  // [t*16, t*16+16); shfl prefix + LDS cross-wave merge orders the scatter.
  // Slots [cnt, MAXN) padded with p (self) so downstream loops are fixed-trip.
  int p = blockIdx.x - QKVB;
  int md = detect_mode((const unsigned char*)mask);
  unsigned int bits = 0;  // bit i => column t*16+i is a neighbor

  if (md == 0) {
    uint4 v = reinterpret_cast<const uint4*>((const unsigned char*)mask +
                                             (size_t)p * PP)[t];
    unsigned int w4[4] = {v.x, v.y, v.z, v.w};
#pragma unroll
    for (int wi = 0; wi < 4; ++wi) {
      unsigned int w = w4[wi];
      unsigned int nz = ((((w & 0x7F7F7F7Fu) + 0x7F7F7F7Fu) | w) & 0x80808080u);
      unsigned int xbit = (nz >> 7) & 0x01010101u;
      unsigned int b4 = (xbit | (xbit >> 7) | (xbit >> 14) | (xbit >> 21)) & 0xFu;
      bits |= b4 << (wi * 4);
    }
  } else {
    const uint4* base =
        reinterpret_cast<const uint4*>((const unsigned int*)mask + (size_t)p * PP) +
        t * 4;
#pragma unroll
    for (int c = 0; c < 4; ++c) {
      uint4 v = base[c];
      unsigned int b4 = (v.x ? 1u : 0u) | (v.y ? 2u : 0u) |
                        (v.z ? 4u : 0u) | (v.w ? 8u : 0u);
      bits |= b4 << (c * 4);
    }
  }

  int cnt = __popc(bits);
  int pre = cnt;  // inclusive prefix within wave
#pragma unroll
  for (int d = 1; d < 64; d <<= 1) {
    int tt = __shfl_up(pre, d);
    if (lane >= d) pre += tt;
  }
  __shared__ int wsum[4];
  if (lane == 63) wsum[wv] = pre;
  __syncthreads();
  int woff = 0;
#pragma unroll
  for (int w = 0; w < 4; ++w)
    if (w < wv) woff += wsum[w];
  int base_pos = woff + pre - cnt;  // exclusive global prefix
  unsigned int m = bits;
  while (m) {
    int b = __ffs(m) - 1;
    m &= m - 1;
    if (base_pos < MAXN) nbr_idx[p * MAXN + base_pos] = t * 16 + b;
    ++base_pos;
  }
  int total = wsum[0] + wsum[1] + wsum[2] + wsum[3];
  int cl = total < MAXN ? total : MAXN;
  if (t == 0) nbr_cnt[p] = cl;
  if (t >= cl && t < MAXN) nbr_idx[p * MAXN + t] = p;  // pad with self
}

// ---------------------------------------------------------------------------
// Kernel 2: sparse attention. Block = 256 thr = 2 rows; per row 128 thr:
// h = (sub>>5), il = sub&31.
// Phase 1: lane (h,il) = whole bf16-K dot for neighbor slot il. Softmax = 10
// shuffles. Phase 2: fixed MAXN-trip unrolled PV gather (padded idx).
__global__ void attn_kernel(const float* __restrict__ Qf,
                            const unsigned short* __restrict__ Kb,
                            const unsigned short* __restrict__ Vb,
                            const int* __restrict__ nbr_idx,
                            const int* __restrict__ nbr_cnt,
                            unsigned short* __restrict__ ctxb) {
  int tid = threadIdx.x;
  int r = tid >> 7;                    // 0..1
  int sub = tid & 127;
  int h = sub >> 5, il = sub & 31;
  int row = blockIdx.x * 2 + r;        // 2 | 4096 => no batch straddle
  int b = row >> 12;
  int bBase = b * PP;

  __shared__ int idx_s[2][MAXN];
  __shared__ int cnt_s[2];
  __shared__ float ws_s[2][NH][32];
  if (tid < 2) cnt_s[tid] = nbr_cnt[(blockIdx.x * 2 + tid) & (PP - 1)];
  if (tid >= 128 && tid < 128 + 2 * MAXN) {
    int u = tid - 128;
    idx_s[u / MAXN][u % MAXN] =
        nbr_idx[((blockIdx.x * 2 + u / MAXN) & (PP - 1)) * MAXN + u % MAXN];
  }
  __syncthreads();
  int cnt = cnt_s[r];

  // phase 1: il = neighbor slot (clamped; loads unconditional, score masked)
  int slot = il < MAXN ? il : MAXN - 1;
  int j = idx_s[r][slot];
  const unsigned short* Kr = Kb + (size_t)(bBase + j) * DD + h * HDIM;
  const float4* Qr = reinterpret_cast<const float4*>(Qf + (size_t)row * DD + h * HDIM);
  float acc = 0.f;
#pragma unroll
  for (int c = 0; c < 4; ++c) {
    short8 kk = *reinterpret_cast<const short8*>(Kr + c * 8);
    float4 q0 = Qr[c * 2], q1 = Qr[c * 2 + 1];
    acc = fmaf(q0.x, bf2f((unsigned short)kk[0]), acc);
    acc = fmaf(q0.y, bf2f((unsigned short)kk[1]), acc);
    acc = fmaf(q0.z, bf2f((unsigned short)kk[2]), acc);
    acc = fmaf(q0.w, bf2f((unsigned short)kk[3]), acc);
    acc = fmaf(q1.x, bf2f((unsigned short)kk[4]), acc);
    acc = fmaf(q1.y, bf2f((unsigned short)kk[5]), acc);
    acc = fmaf(q1.z, bf2f((unsigned short)kk[6]), acc);
    acc = fmaf(q1.w, bf2f((unsigned short)kk[7]), acc);
  }
  float s = (il < cnt) ? acc * 0.17677669529663689f : -1e30f;  // 1/sqrt(32)

  float mx = s;
  mx = fmaxf(mx, __shfl_xor(mx, 16));
  mx = fmaxf(mx, __shfl_xor(mx, 8));
  mx = fmaxf(mx, __shfl_xor(mx, 4));
  mx = fmaxf(mx, __shfl_xor(mx, 2));
  mx = fmaxf(mx, __shfl_xor(mx, 1));
  float w = (il < cnt) ? __expf(s - mx) : 0.f;
  float l = w;
  l += __shfl_xor(l, 16);
  l += __shfl_xor(l, 8);
  l += __shfl_xor(l, 4);
  l += __shfl_xor(l, 2);
  l += __shfl_xor(l, 1);
  ws_s[r][h][il] = w / l;  // cnt>=1 (diagonal) => l>0
  __syncthreads();

  // phase 2: il = element e; fixed-trip, all loads independent
  float acc2 = 0.f;
#pragma unroll
  for (int i = 0; i < MAXN; ++i) {
    int jj = idx_s[r][i];
    float wgt = ws_s[r][h][i];
    acc2 = fmaf(wgt, bf2f(Vb[(size_t)(bBase + jj) * DD + h * HDIM + il]), acc2);
  }
  ctxb[(size_t)row * DD + h * HDIM + il] = f2bf(acc2);
}

// ---------------------------------------------------------------------------
// Kernel 3: out = ctx @ Wo^T via MFMA; Wo read f32, converted in-register.
// Grid 512 blocks; block = 4 waves = 16 rows; wave wv covers cols
// [wv*32, wv*32+32) (8 MFMA).
__global__ void oproj_kernel(const unsigned short* __restrict__ ctxb,
                             const float* __restrict__ Wo,
                             float* __restrict__ out) {
  int tid = threadIdx.x;
  int wv = tid >> 6;
  int lane = tid & 63;
  int lrow = lane & 15;
  int kb = lane >> 4;
  int row0 = blockIdx.x * 16;

  floatx4 acc[2];
  acc[0] = (floatx4){0.f, 0.f, 0.f, 0.f};
  acc[1] = (floatx4){0.f, 0.f, 0.f, 0.f};
#pragma unroll
  for (int ks = 0; ks < 4; ++ks) {
    int k0 = ks * 32 + kb * 8;
    short8 a = *reinterpret_cast<const short8*>(ctxb + (size_t)(row0 + lrow) * DD + k0);
#pragma unroll
    for (int c = 0; c < 2; ++c) {
      int col_tile = wv * 2 + c;
      short8 bf = load_frag_f32(Wo + (size_t)(col_tile * 16 + lrow) * DD + k0);
      acc[c] = __builtin_amdgcn_mfma_f32_16x16x32_bf16(a, bf, acc[c], 0, 0, 0);
    }
  }
#pragma unroll
  for (int c = 0; c < 2; ++c)
#pragma unroll
    for (int r = 0; r < 4; ++r)
      out[(size_t)(row0 + kb * 4 + r) * DD + (wv * 2 + c) * 16 + lrow] = acc[c][r];
}

// ---------------------------------------------------------------------------
extern "C" void kernel_launch(void* const* d_in, const int* in_sizes, int n_in,
                              void* d_out, int out_size, void* d_ws, size_t ws_size,
                              hipStream_t stream) {
  const float* x    = (const float*)d_in[0];
  const float* Wq   = (const float*)d_in[1];
  const float* Wk   = (const float*)d_in[2];
  const float* Wv   = (const float*)d_in[3];
  const float* Wo   = (const float*)d_in[4];
  const void*  mask = d_in[5];
  float* out = (float*)d_out;

  char* ws = (char*)d_ws;
  int* nbr_cnt = (int*)(ws + 0);                          //   16 KB
  int* nbr_idx = (int*)(ws + 16384);                      //  384 KB -> 409600
  float* Qf = (float*)(ws + 409600);                      //    4 MB -> 4603904
  unsigned short* Kb = (unsigned short*)(ws + 4603904);   //    2 MB -> 6701056
  unsigned short* Vb = (unsigned short*)(ws + 6701056);   //    2 MB -> 8798208
  unsigned short* ctxb = (unsigned short*)(ws + 8798208); //    2 MB -> 10895360

  fused_compact_qkv<<<QKVB + PP, 256, 0, stream>>>(
      mask, x, Wq, Wk, Wv, nbr_idx, nbr_cnt, Qf, Kb, Vb);
  attn_kernel<<<MROWS / 2, 256, 0, stream>>>(Qf, Kb, Vb, nbr_idx, nbr_cnt, ctxb);
  oproj_kernel<<<MROWS / 16, 256, 0, stream>>>(ctxb, Wo, out);
}